// Round 8
// baseline (41.661 us; speedup 1.0000x reference)
//
#include <hip/hip_runtime.h>
#include <math.h>

// ---------------------------------------------------------------------------
// CNN_88098369175791 — R8: one grid barrier + atomic fan-in tail.
//  * bar1 removed: out1 is computed as per-WG column-partials atomically
//    accumulated into d_ws; last WG (done-counter) finishes sigm+out2.
//  * z_k / w~ / wv 119-iter loops split across 2 threads (e-range halves).
//  * R7's td-score race fixed (scores moved after z's barrier).
// ---------------------------------------------------------------------------

#define NWG 8
#define NT  1024

constexpr int WLEN = 140;
constexpr int TDN  = 14;
constexpr int NOFC = 119;

// d_ws: [0,64) bar0 | [128, 604) accG[119] | [640,644) done | >=1024 G arena
constexpr int G_V16 = 0;   // [32] floats at d_ws+1024

// ---------------- LDS arena (floats) ---------------------------------------
constexpr int EEG = 0;      // [16][119]
constexpr int WA  = 1904;   // 140
constexpr int WB  = 2044;   // 140
constexpr int LNT = 2184;   // [119][16]
constexpr int QP4 = 4088;   // [4][119]
constexpr int Z8  = 4564;   // [2][4][119]
constexpr int UD  = 5516;   // [119]
constexpr int WT2 = 5636;   // [2][119]  w~ halves
constexpr int WV2 = 5876;   // [2][119]  wv halves
constexpr int VT  = 6114;   // [14]
constexpr int SC4 = 6128;   // [4][14]
constexpr int BKQ = 6184;   // [4]
constexpr int CVB = 6188, CBO = 6189;
constexpr int WQH = 6192;   // [16]
constexpr int WKL = 6208;   // [16]
constexpr int WVL = 6224;   // [16]
constexpr int WQT = 6240;   // [16]
constexpr int CST = 6256;   // [1]
constexpr int AC  = 6260;   // [16]
constexpr int BC  = 6276;   // [16]
constexpr int G1L = 6292;   // [30]
constexpr int MXT = 6324;   // [512] max_fc_w transposed [c][16]
constexpr int MXB = 6836;   // [16]
constexpr int KPH = 6852;   // [119][16]
constexpr int VPS = 8756;   // [119][20]
constexpr int S1H = 11136;  // [119]
constexpr int S2H = 11255;  // [119]
constexpr int OWS = 11376;  // [256] out_w[mh] transposed [e][c]
constexpr int OBS = 11632;  // [16]
constexpr int O1C = 11648;  // [119][31] my out1_w COLUMNS (stride 31)
constexpr int O1B = 15340;  // [119]
constexpr int O2WS= 15460;  // [2][119]
constexpr int O2B = 15698;  // [2]
constexpr int FCW = 15700;  // [2]
constexpr int FCB = 15702;  // [2]
constexpr int DD30= 15704;  // [30]
constexpr int HH  = 15736;  // [119]
constexpr int VSL = 15856;  // [32]
constexpr int FLG = 15888;  // [1]
constexpr int ARENA = 15892; // 63,568 B

struct Args {
  const float *x, *td_in_w, *td_in_b, *td_out_w, *td_out_b;
  const float *cm_in_w, *cm_in_b, *cm_out_w, *cm_out_b;
  const float *mc_w, *mc_b, *max_fc_w, *max_fc_b, *proj_w;
  const float *ln_g, *ln_b, *fc_w, *fc_b;
  const float *out1_w, *out1_b, *out2_w, *out2_b;
  float *out;
  unsigned int *bar;   // d_ws base
  float *G;            // d_ws + 1024
};

__device__ __forceinline__ float sigmf(float v) {
  return 1.0f / (1.0f + __expf(-v));
}

__device__ __forceinline__ void gbar(unsigned int* p) {
  __syncthreads();
  if (threadIdx.x == 0) {
    __hip_atomic_fetch_add(p, 1u, __ATOMIC_ACQ_REL, __HIP_MEMORY_SCOPE_AGENT);
    while (__hip_atomic_load(p, __ATOMIC_RELAXED, __HIP_MEMORY_SCOPE_AGENT) < (unsigned)NWG) {
      __builtin_amdgcn_s_sleep(1);
    }
    __builtin_amdgcn_fence(__ATOMIC_ACQUIRE, "agent");
  }
  __syncthreads();
}

__device__ __forceinline__ float dot119(const float* __restrict__ w,
                                        const float* __restrict__ x,
                                        int lane16) {
  float a0 = 0.f, a1 = 0.f;
#pragma unroll
  for (int t = 0; t < 7; ++t) {
    float wv = w[lane16 + 16 * t];
    float xv = x[lane16 + 16 * t];
    if (t & 1) a1 += wv * xv; else a0 += wv * xv;
  }
  if (lane16 < 7) a0 += w[112 + lane16] * x[112 + lane16];
  float acc = a0 + a1;
#pragma unroll
  for (int m = 1; m < 16; m <<= 1) acc += __shfl_xor(acc, m);
  return acc;
}

__device__ __forceinline__ float dot16f4(const float* __restrict__ x,
                                         const float* __restrict__ w) {
  const float4* xa = (const float4*)x; const float4* wa = (const float4*)w;
  float4 x0 = xa[0], x1 = xa[1], x2 = xa[2], x3 = xa[3];
  float4 w0 = wa[0], w1 = wa[1], w2 = wa[2], w3 = wa[3];
  float d0 = x0.x*w0.x + x0.y*w0.y + x0.z*w0.z + x0.w*w0.w;
  float d1 = x1.x*w1.x + x1.y*w1.y + x1.z*w1.z + x1.w*w1.w;
  float d2 = x2.x*w2.x + x2.y*w2.y + x2.z*w2.z + x2.w*w2.w;
  float d3 = x3.x*w3.x + x3.y*w3.y + x3.z*w3.z + x3.w*w3.w;
  return (d0 + d1) + (d2 + d3);
}

__global__ __launch_bounds__(NT) void fused_cnn_kernel(Args a) {
  __shared__ __align__(16) float S[ARENA];
  const int tid = threadIdx.x;
  const int wgid = blockIdx.x;
  const int grp = tid >> 4;
  const int lane16 = tid & 15;
  float* G = a.G;

  const int s  = wgid >> 2;              // 0: A-stream (m0), 1: B-stream (m3)
  const int i0 = (wgid & 3) * 4;         // v16 slots
  const int mh = s ? 3 : 0;              // heavy cm-MHA
  const int lm = s ? 2 : 1;              // folded light cm-MHA
  const int q4 = wgid & 3;
  const int r0 = q4 * 30;
  const int nr = (q4 == 3) ? 29 : 30;
  const int wavX = s ? WB : WA;

  // ---- P0: stage x + all static prefetches -----------------------------
  for (int t = tid; t < 16 * NOFC; t += NT) {
    int c = t / NOFC, tt = t - c * NOFC;
    S[EEG + t] = a.x[(1 + c) * WLEN + (WLEN - NOFC) + tt];
  }
  if (tid < WLEN) {
    S[WA + tid] = a.x[tid];
    S[WB + tid] = a.x[17 * WLEN + tid];
  }
  if (tid < 512) {                       // max_fc_w transposed [c][16]
    int t16 = tid >> 5, c32 = tid & 31;
    S[MXT + c32 * 16 + t16] = a.max_fc_w[tid];
  }
  if (tid < 16)  S[MXB + tid] = a.max_fc_b[tid];
  if (tid < 256) {                       // heavy out_w transposed [e][c]
    int c = tid >> 4, e = tid & 15;
    S[OWS + e * 16 + c] = a.cm_out_w[mh * 256 + tid];
  }
  if (tid < 16)  S[OBS + tid] = a.cm_out_b[mh * 16 + tid];
  for (int idx = tid; idx < 119 * 30; idx += NT) {   // my out1_w columns
    int r = idx / 30, j = idx - r * 30;
    if (j < nr) S[O1C + r * 31 + j] = a.out1_w[r * 238 + s * NOFC + r0 + j];
  }
  if (tid < NOFC) S[O1B + tid] = a.out1_b[tid];
  if (tid < 238)  S[O2WS + tid] = a.out2_w[tid];
  if (tid < 2) {
    S[O2B + tid] = a.out2_b[tid];
    S[FCW + tid] = a.fc_w[tid];
    S[FCB + tid] = a.fc_b[tid];
  }
  __syncthreads();

  // ---- A: qp (4 rows, weight-row reuse) + u ----------------------------
  for (int e = grp; e < NOFC; e += 64) {
    const float* wrow = a.td_in_w + e * NOFC;
    float w0 = wrow[lane16], w1 = wrow[lane16 + 16], w2 = wrow[lane16 + 32],
          w3 = wrow[lane16 + 48], w4 = wrow[lane16 + 64], w5 = wrow[lane16 + 80],
          w6 = wrow[lane16 + 96];
    float wt7 = (lane16 < 7) ? wrow[112 + lane16] : 0.0f;
    float b = a.td_in_b[e];
#pragma unroll
    for (int kk = 0; kk < 4; ++kk) {
      const float* x = S + EEG + (i0 + kk) * NOFC;
      float acc = w0 * x[lane16] + w1 * x[lane16 + 16] + w2 * x[lane16 + 32]
                + w3 * x[lane16 + 48] + w4 * x[lane16 + 64] + w5 * x[lane16 + 80]
                + w6 * x[lane16 + 96];
      if (lane16 < 7) acc += wt7 * x[112 + lane16];
#pragma unroll
      for (int mm = 1; mm < 16; mm <<= 1) acc += __shfl_xor(acc, mm);
      if (lane16 == 0) S[QP4 + kk * NOFC + e] = acc + b;
    }
  }
  if (grp >= 55) {                        // u[d] = mc_w[s] . eeg[:,d]
    int d = (grp - 55) * 16 + lane16;
    if (d < NOFC) {
      float acc = 0.f;
#pragma unroll
      for (int i = 0; i < 16; ++i) acc += a.mc_w[s * 16 + i] * S[EEG + i * NOFC + d];
      S[UD + d] = acc;
    }
  }
  __syncthreads();

  // ---- B: LNT | z halves | bkq | w~ halves | we-vectors ----------------
  if (tid < NOFC) {
    float xv[16]; float mu = 0.f;
#pragma unroll
    for (int c = 0; c < 16; ++c) { xv[c] = S[EEG + c * NOFC + tid]; mu += xv[c]; }
    mu *= (1.0f / 16.0f);
    float var = 0.f;
#pragma unroll
    for (int c = 0; c < 16; ++c) { float d = xv[c] - mu; var += d * d; }
    var *= (1.0f / 16.0f);
    float inv = 1.0f / sqrtf(var + 1e-5f);
#pragma unroll
    for (int c = 0; c < 16; ++c)
      S[LNT + tid * 16 + c] = (xv[c] - mu) * inv * a.ln_g[c] + a.ln_b[c];
  } else if (tid >= 128 && tid < 366) {          // z halves
    int i = tid - 128, half = i / NOFC, t = i - half * NOFC;
    int e0 = half * 60, e1 = half ? NOFC : 60;
    float a0 = 0.f, a1 = 0.f, a2 = 0.f, a3 = 0.f;
    for (int e = e0; e < e1; ++e) {
      float w = a.td_in_w[(NOFC + e) * NOFC + t];
      a0 += S[QP4 + e] * w;
      a1 += S[QP4 + NOFC + e] * w;
      a2 += S[QP4 + 2 * NOFC + e] * w;
      a3 += S[QP4 + 3 * NOFC + e] * w;
    }
    S[Z8 + (half * 4 + 0) * NOFC + t] = a0;
    S[Z8 + (half * 4 + 1) * NOFC + t] = a1;
    S[Z8 + (half * 4 + 2) * NOFC + t] = a2;
    S[Z8 + (half * 4 + 3) * NOFC + t] = a3;
  } else if (tid >= 384 && tid < 448) {          // bkq
    int kk = (tid - 384) >> 4;
    float acc = dot119(S + QP4 + kk * NOFC, a.td_in_b + NOFC, lane16);
    if (lane16 == 0) S[BKQ + kk] = acc;
  } else if (tid >= 448 && tid < 686) {          // w~ halves
    int i = tid - 448, half = i / NOFC, t = i - half * NOFC;
    int d0 = half * 60, d1 = half ? NOFC : 60;
    float acc = 0.f;
    for (int d = d0; d < d1; ++d) acc += S[UD + d] * a.td_out_w[d * NOFC + t];
    S[WT2 + half * NOFC + t] = acc;
  } else if (tid >= 704 && tid < 720) {          // weQ heavy
    int e = tid - 704;
    float acc = 0.f;
#pragma unroll
    for (int c = 0; c < 16; ++c) acc += a.proj_w[s * 16 + c] * a.cm_in_w[(mh * 48 + e) * 16 + c];
    S[WQH + e] = acc;
  } else if (tid >= 720 && tid < 736) {          // weK light
    int e = tid - 720;
    float acc = 0.f;
#pragma unroll
    for (int c = 0; c < 16; ++c) acc += a.proj_w[s * 16 + c] * a.cm_in_w[(lm * 48 + 16 + e) * 16 + c];
    S[WKL + e] = acc;
  } else if (tid >= 736 && tid < 752) {          // weV light
    int e = tid - 736;
    float acc = 0.f;
#pragma unroll
    for (int c = 0; c < 16; ++c) acc += a.proj_w[s * 16 + c] * a.cm_in_w[(lm * 48 + 32 + e) * 16 + c];
    S[WVL + e] = acc;
  }
  __syncthreads();

  // ---- C: wv halves | kp/vp staging | td scores ------------------------
  if (tid < 238) {
    int half = tid / NOFC, t = tid - half * NOFC;
    int e0 = half * 60, e1 = half ? NOFC : 60;
    float acc = 0.f;
    for (int e = e0; e < e1; ++e)
      acc += (S[WT2 + e] + S[WT2 + NOFC + e]) * a.td_in_w[(2 * NOFC + e) * NOFC + t];
    S[WV2 + half * NOFC + t] = acc;
  } else if (tid >= 240 && tid < 560) {
    for (int o = tid - 240; o < 3808; o += 320) {
      if (o < 1904) {
        int u = o >> 4, e = o & 15;
        S[KPH + o] = dot16f4(S + LNT + u * 16, a.cm_in_w + (mh * 48 + 16 + e) * 16)
                     + a.cm_in_b[mh * 48 + 16 + e];
      } else {
        int o2 = o - 1904, u = o2 >> 4, e = o2 & 15;
        S[VPS + u * 20 + e] = dot16f4(S + LNT + u * 16, a.cm_in_w + (mh * 48 + 32 + e) * 16)
                              + a.cm_in_b[mh * 48 + 32 + e];
      }
    }
  }
  if (grp >= 36) {                               // scores (z complete: post-sync)
#pragma unroll
    for (int rnd = 0; rnd < 2; ++rnd) {
      int idx = (grp - 36) + rnd * 28;
      if (idx < 56) {
        int kk = idx / TDN, j = idx - kk * TDN;
        float acc = dot119(S + wavX + j, S + Z8 + kk * NOFC, lane16)
                  + dot119(S + wavX + j, S + Z8 + (4 + kk) * NOFC, lane16);
        if (lane16 == 0)
          S[SC4 + kk * TDN + j] = 0.09166984970282113f * (acc + S[BKQ + kk]);
      }
    }
  }
  __syncthreads();

  // ---- D: vtil | softmax | cvb/cbo | wq~/cst/A/B | s1/s2 ---------------
  if (grp < TDN) {                               // vtil
    float acc = dot119(S + wavX + grp, S + WV2, lane16)
              + dot119(S + wavX + grp, S + WV2 + NOFC, lane16);
    if (lane16 == 0) S[VT + grp] = acc;
  } else if (tid >= 224 && tid < 228) {          // softmax
    int k = tid - 224;
    float* r = S + SC4 + k * TDN;
    float mx = r[0];
#pragma unroll
    for (int j = 1; j < TDN; ++j) mx = fmaxf(mx, r[j]);
    float sum = 0.f;
#pragma unroll
    for (int j = 0; j < TDN; ++j) { float p = __expf(r[j] - mx); r[j] = p; sum += p; }
    float inv = 1.0f / sum;
#pragma unroll
    for (int j = 0; j < TDN; ++j) r[j] *= inv;
  } else if (grp == 15) {                        // cvb = bv . w~
    float acc = dot119(a.td_in_b + 2 * NOFC, S + WT2, lane16)
              + dot119(a.td_in_b + 2 * NOFC, S + WT2 + NOFC, lane16);
    if (lane16 == 0) S[CVB] = acc;
  } else if (grp == 16) {                        // cbo = u . out_b
    float acc = dot119(S + UD, a.td_out_b, lane16);
    if (lane16 == 0) S[CBO] = acc;
  } else if (tid >= 288 && tid < 304) {          // wq~[c]
    int c = tid - 288;
    float acc = 0.f;
#pragma unroll
    for (int e = 0; e < 16; ++e) acc += a.cm_in_w[(lm * 48 + e) * 16 + c] * S[WKL + e];
    S[WQT + c] = acc;
  } else if (tid == 304) {                       // cst
    float acc = 0.f;
#pragma unroll
    for (int e = 0; e < 16; ++e) acc += a.cm_in_b[lm * 48 + e] * S[WKL + e];
    S[CST] = acc;
  } else if (tid >= 320 && tid < 336) {          // A1[c]
    int c = tid - 320;
    float acc = 0.f;
#pragma unroll
    for (int e = 0; e < 16; ++e) acc += a.cm_out_w[lm * 256 + c * 16 + e] * S[WVL + e];
    S[AC + c] = acc;
  } else if (tid >= 336 && tid < 352) {          // B1[c]
    int c = tid - 336;
    float acc = 0.f;
#pragma unroll
    for (int e = 0; e < 16; ++e) acc += a.cm_out_w[lm * 256 + c * 16 + e] * a.cm_in_b[lm * 48 + 32 + e];
    S[BC + c] = acc + a.cm_out_b[lm * 16 + c];
  }
  if (tid >= 512 && tid < 750) {                 // s1/s2
    int idx = tid - 512;
    int u = (idx < NOFC) ? idx : idx - NOFC;
    const float* kpr = S + KPH + u * 16;
    float acc = 0.f;
    if (idx < NOFC) {
#pragma unroll
      for (int e = 0; e < 16; ++e) acc += S[WQH + e] * kpr[e];
      S[S1H + u] = acc;
    } else {
#pragma unroll
      for (int e = 0; e < 16; ++e) acc += a.cm_in_b[mh * 48 + e] * kpr[e];
      S[S2H + u] = acc;
    }
  }
  __syncthreads();

  // ---- E: v16 -> G | g1 -------------------------------------------------
  if (tid < 4) {
    float acc = 0.f;
#pragma unroll
    for (int j = 0; j < TDN; ++j) acc += S[SC4 + tid * TDN + j] * S[VT + j];
    float v = acc + S[CVB] + S[CBO] + a.mc_b[s];
    G[G_V16 + s * 16 + i0 + tid] = fmaxf(v, 0.f);
  } else if (tid >= 32 && tid < 62) {
    int rl = tid - 32;
    if (rl < nr) {
      int t = r0 + rl;
      float acc = S[CST];
#pragma unroll
      for (int c = 0; c < 16; ++c) acc += S[LNT + t * 16 + c] * S[WQT + c];
      S[G1L + rl] = acc;
    }
  }
  gbar(a.bar + 0);

  // ---- argmax (register, replicated) ------------------------------------
  if (tid < 32) S[VSL + tid] = G[G_V16 + tid];
  __syncthreads();
  int mi;
  {
    float wl = S[MXB + lane16];
#pragma unroll
    for (int c = 0; c < 32; ++c) wl += S[MXT + c * 16 + lane16] * S[VSL + c];
    wl = fmaxf(wl, 0.f);
    float mx = wl;
#pragma unroll
    for (int d = 1; d < 16; d <<= 1) mx = fmaxf(mx, __shfl_xor(mx, d));
    int cand = (wl == mx) ? lane16 : 99;
#pragma unroll
    for (int d = 1; d < 16; d <<= 1) cand = min(cand, __shfl_xor(cand, d));
    mi = min(cand, TDN - 1);
  }

  // ---- attention rows -> dd (local) -------------------------------------
  if (grp < nr) {
    const int t = r0 + grp;
    const float wselq = S[wavX + t + mi];
    float p[8];
    float sum = 0.f;
#pragma unroll
    for (int cc = 0; cc < 8; ++cc) {
      int u = lane16 + cc * 16;
      float e1 = 0.f;
      if (u < NOFC)
        e1 = __expf(0.25f * (wselq * S[S1H + u] + S[S2H + u]));
      p[cc] = e1;
      sum += e1;
    }
#pragma unroll
    for (int d = 1; d < 16; d <<= 1) sum += __shfl_xor(sum, d);
    float inv = 1.0f / sum;

    float oa[16];
#pragma unroll
    for (int e = 0; e < 16; ++e) oa[e] = 0.f;
#pragma unroll
    for (int cc = 0; cc < 8; ++cc) {
      int u = lane16 + cc * 16;
      if (u < NOFC) {
        const float4* v4 = (const float4*)(S + VPS + u * 20);
        float4 v0 = v4[0], v1 = v4[1], v2 = v4[2], v3 = v4[3];
        float pv = p[cc];
        oa[0] += pv*v0.x; oa[1] += pv*v0.y; oa[2] += pv*v0.z; oa[3] += pv*v0.w;
        oa[4] += pv*v1.x; oa[5] += pv*v1.y; oa[6] += pv*v1.z; oa[7] += pv*v1.w;
        oa[8] += pv*v2.x; oa[9] += pv*v2.y; oa[10] += pv*v2.z; oa[11] += pv*v2.w;
        oa[12] += pv*v3.x; oa[13] += pv*v3.y; oa[14] += pv*v3.z; oa[15] += pv*v3.w;
      }
    }
#pragma unroll
    for (int e = 0; e < 16; ++e) {
#pragma unroll
      for (int d = 1; d < 16; d <<= 1) oa[e] += __shfl_xor(oa[e], d);
    }
    float oc = S[OBS + lane16];
#pragma unroll
    for (int e = 0; e < 16; ++e) oc += oa[e] * inv * S[OWS + e * 16 + lane16];
    float dA = oc * S[AC + lane16];
    float dB = oc * S[BC + lane16];
#pragma unroll
    for (int d = 1; d < 16; d <<= 1) {
      dA += __shfl_xor(dA, d);
      dB += __shfl_xor(dB, d);
    }
    const float g = S[G1L + grp];
    float s0 = 0.f, s1a = 0.f;
#pragma unroll
    for (int cc = 0; cc < 8; ++cc) {
      int u = lane16 + cc * 16;
      if (u < NOFC) {
        float w = S[wavX + u + mi];
        float e1 = __expf(0.25f * g * w);
        s0 += e1; s1a += e1 * w;
      }
    }
#pragma unroll
    for (int d = 1; d < 16; d <<= 1) {
      s0 += __shfl_xor(s0, d);
      s1a += __shfl_xor(s1a, d);
    }
    float h = s1a / s0;
    float dval = h * dA + dB;
    if (lane16 == 0)
      S[DD30 + grp] = sigmf(S[FCW + s] * dval + S[FCB + s]);
  }
  __syncthreads();

  // ---- out1 column-partials -> atomic accumulate ------------------------
  float* accG = (float*)((char*)a.bar + 128);
  if (tid < NOFC) {
    float acc = 0.f;
    for (int j = 0; j < nr; ++j) acc += S[O1C + tid * 31 + j] * S[DD30 + j];
    atomicAdd(accG + tid, acc);
  }
  __syncthreads();

  // ---- done-counter fan-in; last WG finishes head -----------------------
  unsigned int* done = (unsigned int*)((char*)a.bar + 640);
  if (tid == 0) {
    unsigned old = __hip_atomic_fetch_add(done, 1u, __ATOMIC_ACQ_REL, __HIP_MEMORY_SCOPE_AGENT);
    S[FLG] = (old == NWG - 1) ? 1.0f : 0.0f;
  }
  __syncthreads();
  const bool last = (S[FLG] != 0.0f);
  if (last && tid < NOFC) {
    __builtin_amdgcn_fence(__ATOMIC_ACQUIRE, "agent");
    S[HH + tid] = sigmf(accG[tid] + S[O1B + tid]);
  }
  __syncthreads();
  if (last && tid < 32) {
    int o2 = tid >> 4;
    float a0 = 0.f;
#pragma unroll
    for (int t = 0; t < 8; ++t) {
      int idx = lane16 + 16 * t;
      if (idx < NOFC) a0 += S[O2WS + o2 * NOFC + idx] * S[HH + idx];
    }
    float acc = a0;
#pragma unroll
    for (int mm = 1; mm < 16; mm <<= 1) acc += __shfl_xor(acc, mm);
    if (lane16 == 0) a.out[o2] = sigmf(acc + S[O2B + o2]);
  }
}

extern "C" void kernel_launch(void* const* d_in, const int* in_sizes, int n_in,
                              void* d_out, int out_size, void* d_ws, size_t ws_size,
                              hipStream_t stream) {
  Args a;
  a.x        = (const float*)d_in[0];
  a.td_in_w  = (const float*)d_in[1];
  a.td_in_b  = (const float*)d_in[2];
  a.td_out_w = (const float*)d_in[3];
  a.td_out_b = (const float*)d_in[4];
  a.cm_in_w  = (const float*)d_in[5];
  a.cm_in_b  = (const float*)d_in[6];
  a.cm_out_w = (const float*)d_in[7];
  a.cm_out_b = (const float*)d_in[8];
  a.mc_w     = (const float*)d_in[9];
  a.mc_b     = (const float*)d_in[10];
  a.max_fc_w = (const float*)d_in[11];
  a.max_fc_b = (const float*)d_in[12];
  a.proj_w   = (const float*)d_in[13];
  a.ln_g     = (const float*)d_in[14];
  a.ln_b     = (const float*)d_in[15];
  a.fc_w     = (const float*)d_in[16];
  a.fc_b     = (const float*)d_in[17];
  a.out1_w   = (const float*)d_in[18];
  a.out1_b   = (const float*)d_in[19];
  a.out2_w   = (const float*)d_in[20];
  a.out2_b   = (const float*)d_in[21];
  a.out      = (float*)d_out;
  a.bar      = (unsigned int*)d_ws;
  a.G        = (float*)((char*)d_ws + 1024);

  // zero barrier + accG + done each call (graph replays this).
  hipMemsetAsync(d_ws, 0, 1024, stream);
  fused_cnn_kernel<<<dim3(NWG), dim3(NT), 0, stream>>>(a);
}

// Round 9
// 35.200 us; speedup vs baseline: 1.1836x; 1.1836x over previous
//
#include <hip/hip_runtime.h>
#include <math.h>

// ---------------------------------------------------------------------------
// CNN_88098369175791 — R9: R7 structure (2 gbars, distributed head, 2-atomic
// fan-in) + race fix (scores after z's barrier) + tiled/coalesced matvecs.
// R8's 119-atomic fan-in reverted (cross-XCD atomic ping-pong cost >> gbar).
// ---------------------------------------------------------------------------

#define NWG 8
#define NT  1024

constexpr int WLEN = 140;
constexpr int TDN  = 14;
constexpr int NOFC = 119;

// d_ws: [0,64) bar0 | [64,128) bar1 | +128 acc[2] | +192 done | +512 G arena
constexpr int G_V16 = 0;    // [32] floats (at d_ws+512)
constexpr int G_DD  = 64;   // [238]

// ---------------- LDS arena (floats) ---------------------------------------
constexpr int EEG = 0;      // [16][119]
constexpr int WA  = 1904;   // 140
constexpr int WB  = 2044;   // 140
constexpr int LNT = 2184;   // [119][16]
constexpr int QP4 = 4088;   // [4][119]
constexpr int Z4  = 4564;   // [4][119]
constexpr int UD  = 5040;   // [119]
constexpr int WTT = 5160;   // [119]
constexpr int WVV = 5280;   // [119]
constexpr int VT  = 5400;   // [14]
constexpr int SC4 = 5416;   // [4][14]
constexpr int BKQ = 5472;   // [4]
constexpr int CVB = 5476, CBO = 5477;
constexpr int WQH = 5480;   // [16]
constexpr int WKL = 5496;   // [16]
constexpr int WVL = 5512;   // [16]
constexpr int WQT = 5528;   // [16]
constexpr int CST = 5544;   // [1]
constexpr int AC  = 5548;   // [16]
constexpr int BC  = 5564;   // [16]
constexpr int G1L = 5580;   // [30]
constexpr int MXT = 5612;   // [512] max_fc_w transposed [c][16]
constexpr int MXB = 6124;   // [16]
constexpr int KPH = 6144;   // [119][16]
constexpr int VPS = 8048;   // [119][20] (f4-aligned, padded)
constexpr int S1H = 10428;  // [119]
constexpr int S2H = 10547;  // [119]
constexpr int OWS = 10668;  // [256] out_w[mh] transposed [e][c]
constexpr int OBS = 10924;  // [16]
constexpr int O1W = 10944;  // [15][240] my out1_w rows
constexpr int O1B = 14544;  // [15]
constexpr int O2WS= 14560;  // [30]
constexpr int O2B = 14590;  // [2]
constexpr int FCW = 14592;  // [2]
constexpr int FCB = 14594;  // [2]
constexpr int DDL = 14596;  // [238]
constexpr int HHL = 14834;  // [15]
constexpr int VSL = 14850;  // [32]
constexpr int ARENA = 14884; // 59,536 B

struct Args {
  const float *x, *td_in_w, *td_in_b, *td_out_w, *td_out_b;
  const float *cm_in_w, *cm_in_b, *cm_out_w, *cm_out_b;
  const float *mc_w, *mc_b, *max_fc_w, *max_fc_b, *proj_w;
  const float *ln_g, *ln_b, *fc_w, *fc_b;
  const float *out1_w, *out1_b, *out2_w, *out2_b;
  float *out;
  unsigned int *bar;   // d_ws base
  float *G;            // d_ws + 512
};

__device__ __forceinline__ float sigmf(float v) {
  return 1.0f / (1.0f + __expf(-v));
}

__device__ __forceinline__ void gbar(unsigned int* p) {
  __syncthreads();
  if (threadIdx.x == 0) {
    __hip_atomic_fetch_add(p, 1u, __ATOMIC_ACQ_REL, __HIP_MEMORY_SCOPE_AGENT);
    while (__hip_atomic_load(p, __ATOMIC_RELAXED, __HIP_MEMORY_SCOPE_AGENT) < (unsigned)NWG) {
      __builtin_amdgcn_s_sleep(1);
    }
    __builtin_amdgcn_fence(__ATOMIC_ACQUIRE, "agent");
  }
  __syncthreads();
}

__device__ __forceinline__ float dot119(const float* __restrict__ w,
                                        const float* __restrict__ x,
                                        int lane16) {
  float a0 = 0.f, a1 = 0.f;
#pragma unroll
  for (int t = 0; t < 7; ++t) {
    float wv = w[lane16 + 16 * t];
    float xv = x[lane16 + 16 * t];
    if (t & 1) a1 += wv * xv; else a0 += wv * xv;
  }
  if (lane16 < 7) a0 += w[112 + lane16] * x[112 + lane16];
  float acc = a0 + a1;
#pragma unroll
  for (int m = 1; m < 16; m <<= 1) acc += __shfl_xor(acc, m);
  return acc;
}

__device__ __forceinline__ float dot16f4(const float* __restrict__ x,
                                         const float* __restrict__ w) {
  const float4* xa = (const float4*)x; const float4* wa = (const float4*)w;
  float4 x0 = xa[0], x1 = xa[1], x2 = xa[2], x3 = xa[3];
  float4 w0 = wa[0], w1 = wa[1], w2 = wa[2], w3 = wa[3];
  float d0 = x0.x*w0.x + x0.y*w0.y + x0.z*w0.z + x0.w*w0.w;
  float d1 = x1.x*w1.x + x1.y*w1.y + x1.z*w1.z + x1.w*w1.w;
  float d2 = x2.x*w2.x + x2.y*w2.y + x2.z*w2.z + x2.w*w2.w;
  float d3 = x3.x*w3.x + x3.y*w3.y + x3.z*w3.z + x3.w*w3.w;
  return (d0 + d1) + (d2 + d3);
}

__global__ __launch_bounds__(NT) void fused_cnn_kernel(Args a) {
  __shared__ __align__(16) float S[ARENA];
  const int tid = threadIdx.x;
  const int wgid = blockIdx.x;
  const int grp = tid >> 4;
  const int lane16 = tid & 15;
  float* G = a.G;

  const int s  = wgid >> 2;              // 0: A-stream (m0), 1: B-stream (m3)
  const int i0 = (wgid & 3) * 4;         // v16 slots
  const int mh = s ? 3 : 0;              // heavy cm-MHA
  const int lm = s ? 2 : 1;              // folded light cm-MHA
  const int q4 = wgid & 3;
  const int r0 = q4 * 30;
  const int nr = (q4 == 3) ? 29 : 30;
  const int wavX = s ? WB : WA;

  // ---- P0: stage x + static prefetches ---------------------------------
  for (int t = tid; t < 16 * NOFC; t += NT) {
    int c = t / NOFC, tt = t - c * NOFC;
    S[EEG + t] = a.x[(1 + c) * WLEN + (WLEN - NOFC) + tt];
  }
  if (tid < WLEN) {
    S[WA + tid] = a.x[tid];
    S[WB + tid] = a.x[17 * WLEN + tid];
  }
  if (tid < 512) {                       // max_fc_w transposed [c][16]
    int t16 = tid >> 5, c32 = tid & 31;
    S[MXT + c32 * 16 + t16] = a.max_fc_w[tid];
  }
  if (tid < 16)  S[MXB + tid] = a.max_fc_b[tid];
  if (tid < 256) {                       // heavy out_w transposed [e][c]
    int c = tid >> 4, e = tid & 15;
    S[OWS + e * 16 + c] = a.cm_out_w[mh * 256 + tid];
  }
  if (tid < 16)  S[OBS + tid] = a.cm_out_b[mh * 16 + tid];
  for (int idx = tid; idx < 15 * 238; idx += NT) {    // my out1_w rows
    int rl = idx / 238, c = idx - rl * 238;
    int r = wgid * 15 + rl;
    S[O1W + rl * 240 + c] = (r < NOFC) ? a.out1_w[r * 238 + c] : 0.0f;
  }
  if (tid < 15) {
    int r = wgid * 15 + tid;
    S[O1B + tid] = (r < NOFC) ? a.out1_b[r] : 0.0f;
  }
  if (tid < 30) {
    int o = tid / 15, j = tid - o * 15;
    int r = wgid * 15 + j;
    S[O2WS + tid] = (r < NOFC) ? a.out2_w[o * NOFC + r] : 0.0f;
  }
  if (tid < 2) {
    S[O2B + tid] = a.out2_b[tid];
    S[FCW + tid] = a.fc_w[tid];
    S[FCB + tid] = a.fc_b[tid];
  }
  __syncthreads();

  // ---- A: qp (4 rows, weight-row reuse) + u ----------------------------
  for (int e = grp; e < NOFC; e += 64) {
    const float* wrow = a.td_in_w + e * NOFC;
    float w0 = wrow[lane16], w1 = wrow[lane16 + 16], w2 = wrow[lane16 + 32],
          w3 = wrow[lane16 + 48], w4 = wrow[lane16 + 64], w5 = wrow[lane16 + 80],
          w6 = wrow[lane16 + 96];
    float wt7 = (lane16 < 7) ? wrow[112 + lane16] : 0.0f;
    float b = a.td_in_b[e];
#pragma unroll
    for (int kk = 0; kk < 4; ++kk) {
      const float* x = S + EEG + (i0 + kk) * NOFC;
      float acc = w0 * x[lane16] + w1 * x[lane16 + 16] + w2 * x[lane16 + 32]
                + w3 * x[lane16 + 48] + w4 * x[lane16 + 64] + w5 * x[lane16 + 80]
                + w6 * x[lane16 + 96];
      if (lane16 < 7) acc += wt7 * x[112 + lane16];
#pragma unroll
      for (int mm = 1; mm < 16; mm <<= 1) acc += __shfl_xor(acc, mm);
      if (lane16 == 0) S[QP4 + kk * NOFC + e] = acc + b;
    }
  }
  if (grp >= 55) {                        // u[d] = mc_w[s] . eeg[:,d]
    int d = (grp - 55) * 16 + lane16;
    if (d < NOFC) {
      float acc = 0.f;
#pragma unroll
      for (int i = 0; i < 16; ++i) acc += a.mc_w[s * 16 + i] * S[EEG + i * NOFC + d];
      S[UD + d] = acc;
    }
  }
  __syncthreads();

  // ---- B: z (thread/col, 4 acc) | w~ | LNT | bkq | we-vectors ----------
  if (tid < NOFC) {                       // z_k[t], coalesced col reads
    float a0 = 0.f, a1 = 0.f, a2 = 0.f, a3 = 0.f;
    const float* base = a.td_in_w + NOFC * NOFC + tid;
    for (int e = 0; e < NOFC; ++e) {
      float w = base[e * NOFC];
      a0 += S[QP4 + e] * w;
      a1 += S[QP4 + NOFC + e] * w;
      a2 += S[QP4 + 2 * NOFC + e] * w;
      a3 += S[QP4 + 3 * NOFC + e] * w;
    }
    S[Z4 + tid] = a0; S[Z4 + NOFC + tid] = a1;
    S[Z4 + 2 * NOFC + tid] = a2; S[Z4 + 3 * NOFC + tid] = a3;
  } else if (tid >= 128 && tid < 128 + NOFC) {   // w~[t] = u . out_w[:,t]
    int t = tid - 128;
    float acc = 0.f;
    const float* base = a.td_out_w + t;
    for (int d = 0; d < NOFC; ++d) acc += S[UD + d] * base[d * NOFC];
    S[WTT + t] = acc;
  } else if (tid >= 256 && tid < 256 + NOFC) {   // LNT column
    int t = tid - 256;
    float xv[16]; float mu = 0.f;
#pragma unroll
    for (int c = 0; c < 16; ++c) { xv[c] = S[EEG + c * NOFC + t]; mu += xv[c]; }
    mu *= (1.0f / 16.0f);
    float var = 0.f;
#pragma unroll
    for (int c = 0; c < 16; ++c) { float d = xv[c] - mu; var += d * d; }
    var *= (1.0f / 16.0f);
    float inv = 1.0f / sqrtf(var + 1e-5f);
#pragma unroll
    for (int c = 0; c < 16; ++c)
      S[LNT + t * 16 + c] = (xv[c] - mu) * inv * a.ln_g[c] + a.ln_b[c];
  } else if (tid >= 384 && tid < 448) {          // bkq
    int kk = (tid - 384) >> 4;
    float acc = dot119(S + QP4 + kk * NOFC, a.td_in_b + NOFC, lane16);
    if (lane16 == 0) S[BKQ + kk] = acc;
  } else if (tid >= 448 && tid < 464) {          // weQ heavy
    int e = tid - 448;
    float acc = 0.f;
#pragma unroll
    for (int c = 0; c < 16; ++c) acc += a.proj_w[s * 16 + c] * a.cm_in_w[(mh * 48 + e) * 16 + c];
    S[WQH + e] = acc;
  } else if (tid >= 464 && tid < 480) {          // weK light
    int e = tid - 464;
    float acc = 0.f;
#pragma unroll
    for (int c = 0; c < 16; ++c) acc += a.proj_w[s * 16 + c] * a.cm_in_w[(lm * 48 + 16 + e) * 16 + c];
    S[WKL + e] = acc;
  } else if (tid >= 480 && tid < 496) {          // weV light
    int e = tid - 480;
    float acc = 0.f;
#pragma unroll
    for (int c = 0; c < 16; ++c) acc += a.proj_w[s * 16 + c] * a.cm_in_w[(lm * 48 + 32 + e) * 16 + c];
    S[WVL + e] = acc;
  }
  __syncthreads();

  // ---- C: wv | kp/vp staging | td scores (race-free: z done in B) ------
  if (tid < NOFC) {                       // wv[t] = w~ . Wv[:,t]
    float acc = 0.f;
    const float* base = a.td_in_w + 2 * NOFC * NOFC + tid;
    for (int e = 0; e < NOFC; ++e) acc += S[WTT + e] * base[e * NOFC];
    S[WVV + tid] = acc;
  } else if (tid >= 128 && tid < 560) {   // kp/vp for mh (432 threads, 9 rds)
    for (int o = tid - 128; o < 3808; o += 432) {
      if (o < 1904) {
        int u = o >> 4, e = o & 15;
        S[KPH + o] = dot16f4(S + LNT + u * 16, a.cm_in_w + (mh * 48 + 16 + e) * 16)
                     + a.cm_in_b[mh * 48 + 16 + e];
      } else {
        int o2 = o - 1904, u = o2 >> 4, e = o2 & 15;
        S[VPS + u * 20 + e] = dot16f4(S + LNT + u * 16, a.cm_in_w + (mh * 48 + 32 + e) * 16)
                              + a.cm_in_b[mh * 48 + 32 + e];
      }
    }
  }
  if (grp >= 36) {                        // scores, 2 rounds
#pragma unroll
    for (int rnd = 0; rnd < 2; ++rnd) {
      int idx = (grp - 36) + rnd * 28;
      if (idx < 56) {
        int kk = idx / TDN, j = idx - kk * TDN;
        float acc = dot119(S + wavX + j, S + Z4 + kk * NOFC, lane16);
        if (lane16 == 0)
          S[SC4 + kk * TDN + j] = 0.09166984970282113f * (acc + S[BKQ + kk]);
      }
    }
  }
  __syncthreads();

  // ---- D: vtil | softmax | cvb/cbo | wq~/cst/A1/B1 | s1/s2 -------------
  if (grp < TDN) {                        // vtil
    float acc = dot119(S + wavX + grp, S + WVV, lane16);
    if (lane16 == 0) S[VT + grp] = acc;
  } else if (tid >= 224 && tid < 228) {   // softmax
    int k = tid - 224;
    float* r = S + SC4 + k * TDN;
    float mx = r[0];
#pragma unroll
    for (int j = 1; j < TDN; ++j) mx = fmaxf(mx, r[j]);
    float sum = 0.f;
#pragma unroll
    for (int j = 0; j < TDN; ++j) { float p = __expf(r[j] - mx); r[j] = p; sum += p; }
    float inv = 1.0f / sum;
#pragma unroll
    for (int j = 0; j < TDN; ++j) r[j] *= inv;
  } else if (grp == 15) {                 // cvb = bv . w~
    float acc = dot119(a.td_in_b + 2 * NOFC, S + WTT, lane16);
    if (lane16 == 0) S[CVB] = acc;
  } else if (grp == 16) {                 // cbo = u . out_b
    float acc = dot119(S + UD, a.td_out_b, lane16);
    if (lane16 == 0) S[CBO] = acc;
  } else if (tid >= 288 && tid < 304) {   // wq~[c]
    int c = tid - 288;
    float acc = 0.f;
#pragma unroll
    for (int e = 0; e < 16; ++e) acc += a.cm_in_w[(lm * 48 + e) * 16 + c] * S[WKL + e];
    S[WQT + c] = acc;
  } else if (tid == 304) {                // cst
    float acc = 0.f;
#pragma unroll
    for (int e = 0; e < 16; ++e) acc += a.cm_in_b[lm * 48 + e] * S[WKL + e];
    S[CST] = acc;
  } else if (tid >= 320 && tid < 336) {   // A1[c]
    int c = tid - 320;
    float acc = 0.f;
#pragma unroll
    for (int e = 0; e < 16; ++e) acc += a.cm_out_w[lm * 256 + c * 16 + e] * S[WVL + e];
    S[AC + c] = acc;
  } else if (tid >= 336 && tid < 352) {   // B1[c]
    int c = tid - 336;
    float acc = 0.f;
#pragma unroll
    for (int e = 0; e < 16; ++e) acc += a.cm_out_w[lm * 256 + c * 16 + e] * a.cm_in_b[lm * 48 + 32 + e];
    S[BC + c] = acc + a.cm_out_b[lm * 16 + c];
  }
  if (tid >= 512 && tid < 750) {          // s1/s2
    int idx = tid - 512;
    int u = (idx < NOFC) ? idx : idx - NOFC;
    const float* kpr = S + KPH + u * 16;
    float acc = 0.f;
    if (idx < NOFC) {
#pragma unroll
      for (int e = 0; e < 16; ++e) acc += S[WQH + e] * kpr[e];
      S[S1H + u] = acc;
    } else {
#pragma unroll
      for (int e = 0; e < 16; ++e) acc += a.cm_in_b[mh * 48 + e] * kpr[e];
      S[S2H + u] = acc;
    }
  }
  __syncthreads();

  // ---- E: v16 -> G | g1 -------------------------------------------------
  if (tid < 4) {
    float acc = 0.f;
#pragma unroll
    for (int j = 0; j < TDN; ++j) acc += S[SC4 + tid * TDN + j] * S[VT + j];
    float v = acc + S[CVB] + S[CBO] + a.mc_b[s];
    G[G_V16 + s * 16 + i0 + tid] = fmaxf(v, 0.f);
  } else if (tid >= 32 && tid < 62) {
    int rl = tid - 32;
    if (rl < nr) {
      int t = r0 + rl;
      float acc = S[CST];
#pragma unroll
      for (int c = 0; c < 16; ++c) acc += S[LNT + t * 16 + c] * S[WQT + c];
      S[G1L + rl] = acc;
    }
  }
  gbar(a.bar + 0);

  // ---- argmax (register, replicated) ------------------------------------
  if (tid < 32) S[VSL + tid] = G[G_V16 + tid];
  __syncthreads();
  int mi;
  {
    float wl = S[MXB + lane16];
#pragma unroll
    for (int c = 0; c < 32; ++c) wl += S[MXT + c * 16 + lane16] * S[VSL + c];
    wl = fmaxf(wl, 0.f);
    float mx = wl;
#pragma unroll
    for (int d = 1; d < 16; d <<= 1) mx = fmaxf(mx, __shfl_xor(mx, d));
    int cand = (wl == mx) ? lane16 : 99;
#pragma unroll
    for (int d = 1; d < 16; d <<= 1) cand = min(cand, __shfl_xor(cand, d));
    mi = min(cand, TDN - 1);
  }

  // ---- attention rows -> G_DD -------------------------------------------
  if (grp < nr) {
    const int t = r0 + grp;
    const float wselq = S[wavX + t + mi];
    float p[8];
    float sum = 0.f;
#pragma unroll
    for (int cc = 0; cc < 8; ++cc) {
      int u = lane16 + cc * 16;
      float e1 = 0.f;
      if (u < NOFC)
        e1 = __expf(0.25f * (wselq * S[S1H + u] + S[S2H + u]));
      p[cc] = e1;
      sum += e1;
    }
#pragma unroll
    for (int d = 1; d < 16; d <<= 1) sum += __shfl_xor(sum, d);
    float inv = 1.0f / sum;

    float oa[16];
#pragma unroll
    for (int e = 0; e < 16; ++e) oa[e] = 0.f;
#pragma unroll
    for (int cc = 0; cc < 8; ++cc) {
      int u = lane16 + cc * 16;
      if (u < NOFC) {
        const float4* v4 = (const float4*)(S + VPS + u * 20);
        float4 v0 = v4[0], v1 = v4[1], v2 = v4[2], v3 = v4[3];
        float pv = p[cc];
        oa[0] += pv*v0.x; oa[1] += pv*v0.y; oa[2] += pv*v0.z; oa[3] += pv*v0.w;
        oa[4] += pv*v1.x; oa[5] += pv*v1.y; oa[6] += pv*v1.z; oa[7] += pv*v1.w;
        oa[8] += pv*v2.x; oa[9] += pv*v2.y; oa[10] += pv*v2.z; oa[11] += pv*v2.w;
        oa[12] += pv*v3.x; oa[13] += pv*v3.y; oa[14] += pv*v3.z; oa[15] += pv*v3.w;
      }
    }
#pragma unroll
    for (int e = 0; e < 16; ++e) {
#pragma unroll
      for (int d = 1; d < 16; d <<= 1) oa[e] += __shfl_xor(oa[e], d);
    }
    float oc = S[OBS + lane16];
#pragma unroll
    for (int e = 0; e < 16; ++e) oc += oa[e] * inv * S[OWS + e * 16 + lane16];
    float dA = oc * S[AC + lane16];
    float dB = oc * S[BC + lane16];
#pragma unroll
    for (int d = 1; d < 16; d <<= 1) {
      dA += __shfl_xor(dA, d);
      dB += __shfl_xor(dB, d);
    }
    const float g = S[G1L + grp];
    float s0 = 0.f, s1a = 0.f;
#pragma unroll
    for (int cc = 0; cc < 8; ++cc) {
      int u = lane16 + cc * 16;
      if (u < NOFC) {
        float w = S[wavX + u + mi];
        float e1 = __expf(0.25f * g * w);
        s0 += e1; s1a += e1 * w;
      }
    }
#pragma unroll
    for (int d = 1; d < 16; d <<= 1) {
      s0 += __shfl_xor(s0, d);
      s1a += __shfl_xor(s1a, d);
    }
    float h = s1a / s0;
    float dval = h * dA + dB;
    if (lane16 == 0)
      G[G_DD + s * NOFC + t] = sigmf(S[FCW + s] * dval + S[FCB + s]);
  }
  gbar(a.bar + 16);

  // ---- head: dd -> LDS, 15 out1 rows, out2 via 2 atomics ----------------
  if (tid < 238) S[DDL + tid] = G[G_DD + tid];
  __syncthreads();
  if (grp < 15) {
    int r = wgid * 15 + grp;
    float acc = 0.f;
#pragma unroll
    for (int k = 0; k < 15; ++k) {
      int c = lane16 + 16 * k;
      if (c < 238) acc += S[O1W + grp * 240 + c] * S[DDL + c];
    }
#pragma unroll
    for (int d = 1; d < 16; d <<= 1) acc += __shfl_xor(acc, d);
    if (lane16 == 0)
      S[HHL + grp] = (r < NOFC) ? sigmf(acc + S[O1B + grp]) : 0.0f;
  }
  __syncthreads();
  if (tid == 0) {
    float p0 = 0.f, p1 = 0.f;
#pragma unroll
    for (int j = 0; j < 15; ++j) {
      p0 += S[O2WS + j] * S[HHL + j];
      p1 += S[O2WS + 15 + j] * S[HHL + j];
    }
    float* acc = (float*)((char*)a.bar + 128);
    unsigned int* done = (unsigned int*)((char*)a.bar + 192);
    __hip_atomic_fetch_add(acc + 0, p0, __ATOMIC_RELAXED, __HIP_MEMORY_SCOPE_AGENT);
    __hip_atomic_fetch_add(acc + 1, p1, __ATOMIC_RELAXED, __HIP_MEMORY_SCOPE_AGENT);
    unsigned old = __hip_atomic_fetch_add(done, 1u, __ATOMIC_ACQ_REL, __HIP_MEMORY_SCOPE_AGENT);
    if (old == NWG - 1) {
      __builtin_amdgcn_fence(__ATOMIC_ACQUIRE, "agent");
      float a0 = __hip_atomic_load(acc + 0, __ATOMIC_RELAXED, __HIP_MEMORY_SCOPE_AGENT);
      float a1 = __hip_atomic_load(acc + 1, __ATOMIC_RELAXED, __HIP_MEMORY_SCOPE_AGENT);
      a.out[0] = sigmf(a0 + S[O2B + 0]);
      a.out[1] = sigmf(a1 + S[O2B + 1]);
    }
  }
}

extern "C" void kernel_launch(void* const* d_in, const int* in_sizes, int n_in,
                              void* d_out, int out_size, void* d_ws, size_t ws_size,
                              hipStream_t stream) {
  Args a;
  a.x        = (const float*)d_in[0];
  a.td_in_w  = (const float*)d_in[1];
  a.td_in_b  = (const float*)d_in[2];
  a.td_out_w = (const float*)d_in[3];
  a.td_out_b = (const float*)d_in[4];
  a.cm_in_w  = (const float*)d_in[5];
  a.cm_in_b  = (const float*)d_in[6];
  a.cm_out_w = (const float*)d_in[7];
  a.cm_out_b = (const float*)d_in[8];
  a.mc_w     = (const float*)d_in[9];
  a.mc_b     = (const float*)d_in[10];
  a.max_fc_w = (const float*)d_in[11];
  a.max_fc_b = (const float*)d_in[12];
  a.proj_w   = (const float*)d_in[13];
  a.ln_g     = (const float*)d_in[14];
  a.ln_b     = (const float*)d_in[15];
  a.fc_w     = (const float*)d_in[16];
  a.fc_b     = (const float*)d_in[17];
  a.out1_w   = (const float*)d_in[18];
  a.out1_b   = (const float*)d_in[19];
  a.out2_w   = (const float*)d_in[20];
  a.out2_b   = (const float*)d_in[21];
  a.out      = (float*)d_out;
  a.bar      = (unsigned int*)d_ws;
  a.G        = (float*)((char*)d_ws + 512);

  // zero barriers + out2 accumulators + done counter each call.
  hipMemsetAsync(d_ws, 0, 512, stream);
  fused_cnn_kernel<<<dim3(NWG), dim3(NT), 0, stream>>>(a);
}